// Round 1
// baseline (343.735 us; speedup 1.0000x reference)
//
#include <hip/hip_runtime.h>
#include <math.h>

// Problem constants (match reference): B=64, K=4096, N=256.
// out[b*K+k] = tanh( dot(x[b,k,:], W[k,:]) ), N=256 reduction.
// Memory-bound: 256 MiB x read dominates. One wave (64 lanes) per output
// row: lane i loads float4 at n=4*i -> 64*16B = 1 KiB contiguous per wave.
constexpr int GK = 4096;   // weight groups (power of 2)
constexpr int GN = 256;    // group size

__global__ __launch_bounds__(256) void ginn_input_layer(
    const float* __restrict__ x,   // [B*K, N]
    const float* __restrict__ W,   // [K, N]
    float* __restrict__ out)       // [B*K]
{
    const int lane = threadIdx.x & 63;
    const int wave = threadIdx.x >> 6;                  // 4 waves/block
    const long long row = (long long)blockIdx.x * 4 + wave;  // 0 .. B*K-1
    const int k = (int)(row & (GK - 1));                // k = row % K

    const float4 xv = ((const float4*)(x + row * GN))[lane];
    const float4 wv = ((const float4*)(W + (long long)k * GN))[lane];

    float s = xv.x * wv.x + xv.y * wv.y + xv.z * wv.z + xv.w * wv.w;

    // wave-64 butterfly reduction
    #pragma unroll
    for (int off = 32; off > 0; off >>= 1)
        s += __shfl_down(s, off, 64);

    if (lane == 0)
        out[row] = tanhf(s);
}

extern "C" void kernel_launch(void* const* d_in, const int* in_sizes, int n_in,
                              void* d_out, int out_size, void* d_ws, size_t ws_size,
                              hipStream_t stream) {
    const float* x = (const float*)d_in[0];   // [B,K,N] fp32
    const float* W = (const float*)d_in[1];   // [K,N]   fp32
    float* out = (float*)d_out;               // [B,K]   fp32

    const int rows = out_size;                // B*K = 262144
    const int blocks = rows / 4;              // 4 waves (rows) per 256-thread block
    ginn_input_layer<<<blocks, 256, 0, stream>>>(x, W, out);
}

// Round 2
// 339.017 us; speedup vs baseline: 1.0139x; 1.0139x over previous
//
#include <hip/hip_runtime.h>
#include <math.h>

// out[b*K+k] = tanh( dot(x[b,k,:], W[k,:]) ), B=64, K=4096, N=256.
// Pure HBM-bandwidth problem: x = 256 MiB streamed once, W = 4 MiB (L2-hot).
// One wave per row (64 lanes x float4 = 256 floats = one row, fully coalesced).
// Each wave handles 16 consecutive rows, 4 at a time for ILP (8 float4 loads
// in flight per lane). Rows-per-wave=16 divides K=4096, so a wave's 16 rows
// never cross a batch boundary -> W rows are the 16 consecutive k's.
constexpr int GK = 4096;
constexpr int GN = 256;
constexpr int ROWS_PER_WAVE = 16;

typedef float f32x4 __attribute__((ext_vector_type(4)));

__global__ __launch_bounds__(256) void ginn_input_layer(
    const float* __restrict__ x,   // [B*K, N]
    const float* __restrict__ W,   // [K, N]
    float* __restrict__ out)       // [B*K]
{
    const int lane   = threadIdx.x & 63;
    const int waveId = (int)((blockIdx.x * blockDim.x + threadIdx.x) >> 6);
    const long long row0 = (long long)waveId * ROWS_PER_WAVE;
    const int k0 = (int)(row0 & (GK - 1));   // 16-row window stays within one b

    // lane-offset base pointers (stride between consecutive rows = 64 f32x4)
    const f32x4* xp = (const f32x4*)(x + row0 * GN) + lane;
    const f32x4* wp = (const f32x4*)(W + (long long)k0 * GN) + lane;

    #pragma unroll
    for (int rb = 0; rb < ROWS_PER_WAVE; rb += 4) {
        f32x4 xv[4], wv[4];
        #pragma unroll
        for (int j = 0; j < 4; ++j) {
            xv[j] = __builtin_nontemporal_load(xp + (long long)(rb + j) * (GN / 4));
            wv[j] = wp[(long long)(rb + j) * (GN / 4)];
        }
        float s[4];
        #pragma unroll
        for (int j = 0; j < 4; ++j) {
            s[j] = fmaf(xv[j].x, wv[j].x,
                   fmaf(xv[j].y, wv[j].y,
                   fmaf(xv[j].z, wv[j].z, xv[j].w * wv[j].w)));
        }
        // batched wave-64 butterfly: 4 independent reduction chains interleave
        #pragma unroll
        for (int off = 32; off > 0; off >>= 1) {
            #pragma unroll
            for (int j = 0; j < 4; ++j)
                s[j] += __shfl_xor(s[j], off, 64);
        }
        if (lane == 0) {
            f32x4 o;
            o.x = tanhf(s[0]); o.y = tanhf(s[1]);
            o.z = tanhf(s[2]); o.w = tanhf(s[3]);
            // row0+rb is a multiple of 4 -> 16B-aligned store
            *(f32x4*)(out + row0 + rb) = o;
        }
    }
}

extern "C" void kernel_launch(void* const* d_in, const int* in_sizes, int n_in,
                              void* d_out, int out_size, void* d_ws, size_t ws_size,
                              hipStream_t stream) {
    const float* x = (const float*)d_in[0];   // [B,K,N] fp32
    const float* W = (const float*)d_in[1];   // [K,N]   fp32
    float* out = (float*)d_out;               // [B,K]   fp32

    // 4 waves/block * 16 rows/wave = 64 rows per block
    const int blocks = out_size / (4 * ROWS_PER_WAVE);   // 262144/64 = 4096
    ginn_input_layer<<<blocks, 256, 0, stream>>>(x, W, out);
}